// Round 8
// baseline (289.409 us; speedup 1.0000x reference)
//
#include <hip/hip_runtime.h>
#include <math.h>

#define FIN 128
#define NH 8
#define HC 128
#define HD (NH*HC)   // 1024
#define NC 18
#define NW2 32       // w2t padded rows
#define NEG 0.2f

typedef __attribute__((ext_vector_type(8))) short bf16x8;
typedef __attribute__((ext_vector_type(4))) float f32x4;

__device__ __forceinline__ float lrelu(float v){ return v > 0.f ? v : NEG*v; }

__device__ __forceinline__ unsigned short f2b(float f){
  unsigned u = __float_as_uint(f);
  unsigned r = (u + 0x7fffu + ((u >> 16) & 1u)) >> 16;
  return (unsigned short)r;
}
__device__ __forceinline__ float b2f_lo(unsigned u){ return __uint_as_float(u << 16); }
__device__ __forceinline__ float b2f_hi(unsigned u){ return __uint_as_float(u & 0xffff0000u); }

__device__ __forceinline__ void acc8(float* a, float w, uint4 r){
  a[0] += w*b2f_lo(r.x); a[1] += w*b2f_hi(r.x);
  a[2] += w*b2f_lo(r.y); a[3] += w*b2f_hi(r.y);
  a[4] += w*b2f_lo(r.z); a[5] += w*b2f_hi(r.z);
  a[6] += w*b2f_lo(r.w); a[7] += w*b2f_hi(r.w);
}

// ---------------- scan: thread-serial 2-pass ----------------
__global__ __launch_bounds__(1024) void scan_k(const int* __restrict__ deg, int N,
                                               int* __restrict__ off, int* __restrict__ cursor){
  __shared__ int wsum[16];
  int t = threadIdx.x, lane = t & 63, wid = t >> 6;
  int PER = (N + 1023) >> 10;
  int base = t * PER;
  int sum = 0;
  for (int i = 0; i < PER; ++i) {
    int idx = base + i;
    if (idx < N) sum += deg[idx];
  }
  int x = sum;
  #pragma unroll
  for (int o = 1; o < 64; o <<= 1) {
    int y = __shfl_up(x, o, 64);
    if (lane >= o) x += y;
  }
  if (lane == 63) wsum[wid] = x;
  __syncthreads();
  if (wid == 0 && lane < 16) {
    int wv = wsum[lane];
    #pragma unroll
    for (int o = 1; o < 16; o <<= 1) {
      int y = __shfl_up(wv, o, 16);
      if (lane >= o) wv += y;
    }
    wsum[lane] = wv;
  }
  __syncthreads();
  int carry = x - sum + (wid > 0 ? wsum[wid-1] : 0);
  int run = carry;
  for (int i = 0; i < PER; ++i) {
    int idx = base + i;
    if (idx < N) {
      off[idx] = run; cursor[idx] = run;
      run += deg[idx];
    }
  }
  if (base < N && base + PER >= N) off[N] = run;
}

__global__ void scatter_k(const int* __restrict__ ei, int E0, int N,
                          int* __restrict__ cursor, int* __restrict__ csr){
  int e = blockIdx.x*256 + threadIdx.x;
  int tot = E0 + N;
  if (e >= tot) return;
  int src, dst;
  if (e < E0) { src = ei[e]; dst = ei[E0 + e]; }
  else        { src = e - E0; dst = src; }
  int p = atomicAdd(&cursor[dst], 1);
  csr[p] = src;
}

// ---------------- prep: xcvt + w1t + w2t + ut + hist ----------------
__global__ __launch_bounds__(256) void prep_k(const float* __restrict__ x,
    const float* __restrict__ W1, const float* __restrict__ W2,
    const float* __restrict__ a1s, const float* __restrict__ a1d,
    const int* __restrict__ ei,
    unsigned short* __restrict__ xb, unsigned short* __restrict__ w1t,
    unsigned short* __restrict__ w2t, unsigned short* __restrict__ ut_g,
    int* __restrict__ deg,
    int total8, int bX, int E0, int N){
  __shared__ unsigned short sT[FIN][64+2];
  int b = blockIdx.x, t = threadIdx.x;
  if (b < bX) {                       // x -> bf16
    int i = b*256 + t;
    if (i < total8) {
      const float4* p = (const float4*)x + (size_t)i*2;
      float4 a = p[0], c = p[1];
      uint4 o;
      o.x = (unsigned)f2b(a.x) | ((unsigned)f2b(a.y) << 16);
      o.y = (unsigned)f2b(a.z) | ((unsigned)f2b(a.w) << 16);
      o.z = (unsigned)f2b(c.x) | ((unsigned)f2b(c.y) << 16);
      o.w = (unsigned)f2b(c.z) | ((unsigned)f2b(c.w) << 16);
      ((uint4*)xb)[i] = o;
    }
    return;
  }
  b -= bX;
  if (b < 16) {                       // W1 -> bf16 transposed [n][k]
    int n0 = b * 64;
    #pragma unroll
    for (int i = 0; i < 32; ++i) {
      int idx = i*256 + t;
      int k = idx >> 6, nl = idx & 63;
      sT[k][nl] = f2b(W1[(size_t)k*HD + n0 + nl]);
    }
    __syncthreads();
    #pragma unroll
    for (int i = 0; i < 16; ++i) {
      int nl = i*4 + (t >> 6);
      int kp = t & 63;
      unsigned u = (unsigned)sT[2*kp][nl] | ((unsigned)sT[2*kp+1][nl] << 16);
      *(unsigned*)&w1t[(size_t)(n0+nl)*FIN + 2*kp] = u;
    }
    return;
  }
  b -= 16;
  if (b < (NW2*HD)/256) {             // W2 -> bf16 transposed padded [32][1024]
    int idx = b*256 + t;
    int n = idx >> 10, k = idx & 1023;
    w2t[idx] = (n < NC) ? f2b(W2[(size_t)k*NC + n]) : (unsigned short)0;
    return;
  }
  b -= (NW2*HD)/256;
  if (b < 1) {                        // ut[c][k]: folded alpha vectors, c = head*2 + (s/d)
    // 2048 entries, 8 per thread
    #pragma unroll
    for (int e8 = 0; e8 < 8; ++e8) {
      int e = t*8 + e8;
      int c = e >> 7, k = e & 127;
      int h = c >> 1;
      const float* av = (c & 1) ? &a1d[h*HC] : &a1s[h*HC];
      const float* wr = &W1[(size_t)k*HD + h*HC];
      float s = 0.f;
      #pragma unroll 8
      for (int cc = 0; cc < HC; ++cc) s += wr[cc]*av[cc];
      ut_g[c*FIN + k] = f2b(s);
    }
    return;
  }
  b -= 1;
  {                                   // hist
    int e = b*256 + t;
    int tot = E0 + N;
    if (e >= tot) return;
    int dst = (e < E0) ? ei[E0 + e] : (e - E0);
    atomicAdd(&deg[dst], 1);
  }
}

// ---------------- GEMM1 (MFMA bf16) + alpha-via-MFMA + coalesced C-write ----------------
__global__ __launch_bounds__(256) void gemm1_mfma_k(const unsigned short* __restrict__ xb,
    const unsigned short* __restrict__ w1t, const unsigned short* __restrict__ ut_g,
    unsigned short* __restrict__ g1b, float* __restrict__ as1, float* __restrict__ ad1,
    int N){
  __shared__ unsigned short sA[128][136];  // [m][k] staging, reused as bf16 C tile
  __shared__ unsigned short sB[128][136];  // [n][k]
  __shared__ unsigned short sU[16][136];   // folded alpha cols
  int t = threadIdx.x, lane = t & 63, wid = t >> 6;
  int bm = blockIdx.x * 128;
  int head = blockIdx.y;
  int bn = head * 128;
  #pragma unroll
  for (int i = 0; i < 2; ++i) {
    int idx = i*256 + t;
    int row = idx >> 2, seg = idx & 3;
    int gm = bm + row;
    uint4 a0,a1,a2,a3;
    if (gm < N) {
      const uint4* gp = (const uint4*)(xb + (size_t)gm*FIN + seg*32);
      a0 = gp[0]; a1 = gp[1]; a2 = gp[2]; a3 = gp[3];
    } else {
      a0 = a1 = a2 = a3 = make_uint4(0,0,0,0);
    }
    uint4* lp = (uint4*)&sA[row][seg*32];
    lp[0]=a0; lp[1]=a1; lp[2]=a2; lp[3]=a3;
  }
  #pragma unroll
  for (int i = 0; i < 2; ++i) {
    int idx = i*256 + t;
    int row = idx >> 2, seg = idx & 3;
    const uint4* gp = (const uint4*)(w1t + (size_t)(bn + row)*FIN + seg*32);
    uint4* lp = (uint4*)&sB[row][seg*32];
    lp[0]=gp[0]; lp[1]=gp[1]; lp[2]=gp[2]; lp[3]=gp[3];
  }
  bool alpha_blk = (head == 0);
  if (alpha_blk) {   // stage ut: 2048 bf16 = 256 uint4
    int row = t >> 4, seg = t & 15;
    *(uint4*)&sU[row][seg*8] = *(const uint4*)&ut_g[row*FIN + seg*8];
  }
  __syncthreads();
  int wr = wid >> 1, wc = wid & 1;
  int lr = lane & 15, kb = lane >> 4;
  bool alpha_wave = alpha_blk && (wc == 0);
  f32x4 acc[4][4];
  f32x4 accA[4];
  #pragma unroll
  for (int mi = 0; mi < 4; ++mi) {
    f32x4 z = {0.f,0.f,0.f,0.f};
    accA[mi] = z;
    #pragma unroll
    for (int ni = 0; ni < 4; ++ni) acc[mi][ni] = z;
  }
  #pragma unroll
  for (int ks = 0; ks < 4; ++ks) {
    int ko = ks*32 + kb*8;
    bf16x8 a[4], b[4];
    #pragma unroll
    for (int mi = 0; mi < 4; ++mi)
      a[mi] = *(const bf16x8*)&sA[wr*64 + mi*16 + lr][ko];
    #pragma unroll
    for (int ni = 0; ni < 4; ++ni)
      b[ni] = *(const bf16x8*)&sB[wc*64 + ni*16 + lr][ko];
    #pragma unroll
    for (int mi = 0; mi < 4; ++mi)
      #pragma unroll
      for (int ni = 0; ni < 4; ++ni)
        acc[mi][ni] = __builtin_amdgcn_mfma_f32_16x16x32_bf16(a[mi], b[ni], acc[mi][ni], 0, 0, 0);
    if (alpha_wave) {
      bf16x8 ub = *(const bf16x8*)&sU[lr][ko];
      #pragma unroll
      for (int mi = 0; mi < 4; ++mi)
        accA[mi] = __builtin_amdgcn_mfma_f32_16x16x32_bf16(a[mi], ub, accA[mi], 0, 0, 0);
    }
  }
  __syncthreads();   // MFMA LDS reads complete; sA reusable

  // alpha write: C layout col=lane&15 (=lr), row=(lane>>4)*4+reg
  if (alpha_wave) {
    int hcol = lr >> 1;
    float* dst0 = (lr & 1) ? ad1 : as1;
    #pragma unroll
    for (int mi = 0; mi < 4; ++mi)
      #pragma unroll
      for (int r = 0; r < 4; ++r) {
        int row = bm + wr*64 + mi*16 + kb*4 + r;
        if (row < N) dst0[(size_t)row*NH + hcol] = accA[mi][r];
      }
  }
  // stage bf16 C tile for coalesced write
  #pragma unroll
  for (int mi = 0; mi < 4; ++mi)
    #pragma unroll
    for (int ni = 0; ni < 4; ++ni) {
      int col = wc*64 + ni*16 + lr;
      #pragma unroll
      for (int r = 0; r < 4; ++r)
        sA[wr*64 + mi*16 + kb*4 + r][col] = f2b(acc[mi][ni][r]);
    }
  __syncthreads();
  {
    int row = t >> 1, half = t & 1;
    int grow = bm + row;
    if (grow < N) {
      uint4* dst = (uint4*)(g1b + (size_t)grow*HD + bn + half*64);
      const uint4* src = (const uint4*)&sA[row][half*64];
      #pragma unroll
      for (int q = 0; q < 8; ++q) dst[q] = src[q];
    }
  }
}

// ---------------- attn1: half-row per wave (8ch/lane), chunk-8 online softmax gather ----------------
__global__ __launch_bounds__(256) void attn1_k(const unsigned short* __restrict__ g1b,
    const float* __restrict__ as1, const float* __restrict__ ad1,
    const int* __restrict__ off, const int* __restrict__ csr,
    const float* __restrict__ b1, unsigned short* __restrict__ hb, int N){
  int t = threadIdx.x, lane = t & 63, wid = t >> 6;
  int w = blockIdx.x*4 + wid;
  int d = w >> 1, half = w & 1;
  if (d >= N) return;
  int beg = off[d], deg = off[d+1] - beg;
  int hg = half*4 + (lane >> 4);        // head of this lane's 8 channels
  int cb = half*512 + lane*8;           // channel base
  float adg = ad1[d*NH + hg];
  float m = -1e30f, z = 0.f;
  float acc[8];
  #pragma unroll
  for (int i = 0; i < 8; ++i) acc[i] = 0.f;

  int j = 0;
  for (; j + 8 <= deg; j += 8) {
    int s[8];
    #pragma unroll
    for (int q = 0; q < 8; ++q) s[q] = csr[beg+j+q];
    uint4 r[8];
    #pragma unroll
    for (int q = 0; q < 8; ++q) r[q] = *(const uint4*)(g1b + (size_t)s[q]*HD + cb);
    float e[8];
    #pragma unroll
    for (int q = 0; q < 8; ++q) e[q] = lrelu(as1[s[q]*NH+hg] + adg);
    float em = e[0];
    #pragma unroll
    for (int q = 1; q < 8; ++q) em = fmaxf(em, e[q]);
    if (em > m) {
      float sc = __expf(m - em);
      z *= sc;
      #pragma unroll
      for (int i = 0; i < 8; ++i) acc[i] *= sc;
      m = em;
    }
    #pragma unroll
    for (int q = 0; q < 8; ++q) {
      float wv = __expf(e[q] - m);
      z += wv;
      acc8(acc, wv, r[q]);
    }
  }
  for (; j < deg; ++j) {
    int s = csr[beg+j];
    uint4 r = *(const uint4*)(g1b + (size_t)s*HD + cb);
    float e = lrelu(as1[s*NH+hg] + adg);
    if (e > m) {
      float sc = __expf(m - e);
      z *= sc;
      #pragma unroll
      for (int i = 0; i < 8; ++i) acc[i] *= sc;
      m = e;
    }
    float wv = __expf(e - m);
    z += wv;
    acc8(acc, wv, r);
  }

  float zinv = 1.f / (z + 1e-16f);
  float4 bv0 = *(const float4*)&b1[cb];
  float4 bv1 = *(const float4*)&b1[cb+4];
  float v0 = fmaxf(acc[0]*zinv + bv0.x, 0.f);
  float v1 = fmaxf(acc[1]*zinv + bv0.y, 0.f);
  float v2 = fmaxf(acc[2]*zinv + bv0.z, 0.f);
  float v3 = fmaxf(acc[3]*zinv + bv0.w, 0.f);
  float v4 = fmaxf(acc[4]*zinv + bv1.x, 0.f);
  float v5 = fmaxf(acc[5]*zinv + bv1.y, 0.f);
  float v6 = fmaxf(acc[6]*zinv + bv1.z, 0.f);
  float v7 = fmaxf(acc[7]*zinv + bv1.w, 0.f);
  uint4 o;
  o.x = (unsigned)f2b(v0) | ((unsigned)f2b(v1) << 16);
  o.y = (unsigned)f2b(v2) | ((unsigned)f2b(v3) << 16);
  o.z = (unsigned)f2b(v4) | ((unsigned)f2b(v5) << 16);
  o.w = (unsigned)f2b(v6) | ((unsigned)f2b(v7) << 16);
  *(uint4*)(hb + (size_t)d*HD + cb) = o;
}

// ---------------- GEMM2 (MFMA) + fused alpha2 ----------------
__global__ __launch_bounds__(256) void gemm2_k(const unsigned short* __restrict__ hb,
    const unsigned short* __restrict__ w2t, const float* __restrict__ a2s_g, const float* __restrict__ a2d_g,
    float* __restrict__ g2, float* __restrict__ as2, float* __restrict__ ad2, int N){
  __shared__ float red[4][32][32];
  int t = threadIdx.x, lane = t & 63, wid = t >> 6;
  int bm = blockIdx.x * 32;
  int lr = lane & 15, kb = lane >> 4;
  int kw = wid * 256;
  f32x4 acc[2][2];
  #pragma unroll
  for (int mi = 0; mi < 2; ++mi)
    #pragma unroll
    for (int ni = 0; ni < 2; ++ni) {
      f32x4 z = {0.f,0.f,0.f,0.f};
      acc[mi][ni] = z;
    }
  bf16x8 zf;
  #pragma unroll
  for (int q = 0; q < 8; ++q) zf[q] = 0;
  int r0n = bm + lr, r1n = bm + 16 + lr;
  #pragma unroll
  for (int ks = 0; ks < 8; ++ks) {
    int k = kw + ks*32 + kb*8;
    bf16x8 a0 = (r0n < N) ? *(const bf16x8*)&hb[(size_t)r0n*HD + k] : zf;
    bf16x8 a1 = (r1n < N) ? *(const bf16x8*)&hb[(size_t)r1n*HD + k] : zf;
    bf16x8 b0 = *(const bf16x8*)&w2t[(size_t)lr*HD + k];
    bf16x8 b1 = *(const bf16x8*)&w2t[(size_t)(16+lr)*HD + k];
    acc[0][0] = __builtin_amdgcn_mfma_f32_16x16x32_bf16(a0, b0, acc[0][0], 0,0,0);
    acc[0][1] = __builtin_amdgcn_mfma_f32_16x16x32_bf16(a0, b1, acc[0][1], 0,0,0);
    acc[1][0] = __builtin_amdgcn_mfma_f32_16x16x32_bf16(a1, b0, acc[1][0], 0,0,0);
    acc[1][1] = __builtin_amdgcn_mfma_f32_16x16x32_bf16(a1, b1, acc[1][1], 0,0,0);
  }
  #pragma unroll
  for (int mi = 0; mi < 2; ++mi)
    #pragma unroll
    for (int ni = 0; ni < 2; ++ni)
      #pragma unroll
      for (int r = 0; r < 4; ++r)
        red[wid][mi*16 + kb*4 + r][ni*16 + lr] = acc[mi][ni][r];
  __syncthreads();
  int row = t >> 3;
  int c4 = (t & 7) * 4;
  float tot[4];
  #pragma unroll
  for (int q = 0; q < 4; ++q)
    tot[q] = red[0][row][c4+q] + red[1][row][c4+q] + red[2][row][c4+q] + red[3][row][c4+q];
  int n = bm + row;
  float ps = 0.f, pd = 0.f;
  #pragma unroll
  for (int q = 0; q < 4; ++q) {
    int c = c4 + q;
    if (c < NC) {
      ps += tot[q]*a2s_g[c];
      pd += tot[q]*a2d_g[c];
    }
  }
  #pragma unroll
  for (int o = 1; o < 8; o <<= 1) {
    ps += __shfl_xor(ps, o, 8);
    pd += __shfl_xor(pd, o, 8);
  }
  if (n < N) {
    #pragma unroll
    for (int q = 0; q < 4; ++q) {
      int c = c4 + q;
      if (c < NC) g2[(size_t)n*NC + c] = tot[q];
    }
    if ((t & 7) == 0) { as2[n] = ps; ad2[n] = pd; }
  }
}

// ---------------- attn2: wave-per-dst single-pass, 3x18-lane edge-parallel ----------------
__global__ __launch_bounds__(256) void attn2_k(const float* __restrict__ g2,
    const float* __restrict__ as2, const float* __restrict__ ad2,
    const int* __restrict__ off, const int* __restrict__ csr,
    const float* __restrict__ b2, float* __restrict__ out, int N){
  int t = threadIdx.x, lane = t & 63, wid = t >> 6;
  int d = blockIdx.x*4 + wid;
  if (d >= N) return;
  int beg = off[d], deg = off[d+1] - beg;
  float adv = ad2[d];
  int g = lane / 18;
  int c = lane - g*18;
  float m = -1e30f, z = 0.f, acc = 0.f;
  if (g < 3) {
    int j = g;
    for (; j + 3 < deg; j += 6) {
      int sa = csr[beg+j], sb = csr[beg+j+3];
      float va = g2[(size_t)sa*NC + c];
      float vb = g2[(size_t)sb*NC + c];
      float ea = lrelu(as2[sa] + adv);
      float eb = lrelu(as2[sb] + adv);
      float em = fmaxf(ea, eb);
      if (em > m) { float sc = __expf(m - em); z *= sc; acc *= sc; m = em; }
      float wa = __expf(ea - m), wb = __expf(eb - m);
      z += wa + wb;
      acc += wa*va + wb*vb;
    }
    for (; j < deg; j += 3) {
      int s = csr[beg+j];
      float v = g2[(size_t)s*NC + c];
      float e = lrelu(as2[s] + adv);
      if (e > m) { float sc = __expf(m - e); z *= sc; acc *= sc; m = e; }
      float w = __expf(e - m);
      z += w;
      acc += w*v;
    }
  }
  float m0 = __shfl(m, 0),  m1 = __shfl(m, 18), m2 = __shfl(m, 36);
  float M  = fmaxf(m0, fmaxf(m1, m2));
  float e0 = __expf(m0 - M), e1 = __expf(m1 - M), e2 = __expf(m2 - M);
  float z0 = __shfl(z, 0),  z1 = __shfl(z, 18), z2 = __shfl(z, 36);
  int cl = (lane < NC) ? lane : 0;
  float a0 = __shfl(acc, cl), a1 = __shfl(acc, cl+18), a2 = __shfl(acc, cl+36);
  if (lane < NC) {
    float Z = z0*e0 + z1*e1 + z2*e2;
    float A = a0*e0 + a1*e1 + a2*e2;
    out[(size_t)d*NC + lane] = A / (Z + 1e-16f) + b2[lane];
  }
}

extern "C" void kernel_launch(void* const* d_in, const int* in_sizes, int n_in,
                              void* d_out, int out_size, void* d_ws, size_t ws_size,
                              hipStream_t stream){
  const float* x   = (const float*)d_in[0];
  const int*   ei  = (const int*)d_in[1];
  const float* W1  = (const float*)d_in[2];
  const float* a1s = (const float*)d_in[3];
  const float* a1d = (const float*)d_in[4];
  const float* b1  = (const float*)d_in[5];
  const float* W2  = (const float*)d_in[6];
  const float* a2s = (const float*)d_in[7];
  const float* a2d = (const float*)d_in[8];
  const float* b2  = (const float*)d_in[9];
  float* out = (float*)d_out;
  int N  = in_sizes[0] / FIN;
  int E0 = in_sizes[1] / 2;
  int Etot = E0 + N;

  // fp32 region
  float* as1 = (float*)d_ws;                 // N*8
  float* ad1 = as1 + (size_t)N*NH;           // N*8
  float* g2  = ad1 + (size_t)N*NH;           // N*18
  float* as2 = g2 + (size_t)N*NC;            // N
  float* ad2 = as2 + N;                      // N
  // bf16 region
  unsigned short* g1b = (unsigned short*)(ad2 + N);       // N*1024
  unsigned short* hb  = g1b + (size_t)N*HD;               // N*1024
  // int region
  int* deg    = (int*)(hb + (size_t)N*HD);
  int* off    = deg + N;
  int* cursor = off + N + 4;
  int* csr    = cursor + N;
  // bf16 w2t [32][1024] + ut [16][128] after csr
  unsigned short* w2t  = (unsigned short*)(csr + Etot);   // 32*1024
  unsigned short* ut_g = w2t + (size_t)NW2*HD;            // 16*128
  // converted inputs alias hb (hb written only by attn1, after gemm1 consumed xb/w1t)
  unsigned short* xb  = hb;                   // N*FIN
  unsigned short* w1t = hb + (size_t)N*FIN;   // HD*FIN

  hipMemsetAsync(deg, 0, sizeof(int)*(size_t)N, stream);

  int total8 = N*FIN/8;
  int bX = (total8 + 255)/256;
  int bH = (Etot + 255)/256;
  int bW2 = (NW2*HD)/256;   // 128
  prep_k<<<bX + 16 + bW2 + 1 + bH, 256, 0, stream>>>(x, W1, W2, a1s, a1d, ei,
                                                     xb, w1t, w2t, ut_g, deg,
                                                     total8, bX, E0, N);
  scan_k<<<1, 1024, 0, stream>>>(deg, N, off, cursor);
  scatter_k<<<(Etot+255)/256, 256, 0, stream>>>(ei, E0, N, cursor, csr);

  dim3 g1grid((N+127)/128, HD/128);
  gemm1_mfma_k<<<g1grid, 256, 0, stream>>>(xb, w1t, ut_g, g1b, as1, ad1, N);
  attn1_k<<<(2*N+3)/4, 256, 0, stream>>>(g1b, as1, ad1, off, csr, b1, hb, N);
  gemm2_k<<<(N+31)/32, 256, 0, stream>>>(hb, w2t, a2s, a2d, g2, as2, ad2, N);
  attn2_k<<<(N+3)/4, 256, 0, stream>>>(g2, as2, ad2, off, csr, b2, out, N);
}

// Round 9
// 255.099 us; speedup vs baseline: 1.1345x; 1.1345x over previous
//
#include <hip/hip_runtime.h>
#include <math.h>

#define FIN 128
#define NH 8
#define HC 128
#define HD (NH*HC)   // 1024
#define NC 18
#define NW2 32       // w2t padded rows
#define NEG 0.2f

typedef __attribute__((ext_vector_type(8))) short bf16x8;
typedef __attribute__((ext_vector_type(4))) float f32x4;

__device__ __forceinline__ float lrelu(float v){ return v > 0.f ? v : NEG*v; }

__device__ __forceinline__ unsigned short f2b(float f){
  unsigned u = __float_as_uint(f);
  unsigned r = (u + 0x7fffu + ((u >> 16) & 1u)) >> 16;
  return (unsigned short)r;
}
__device__ __forceinline__ float b2f_lo(unsigned u){ return __uint_as_float(u << 16); }
__device__ __forceinline__ float b2f_hi(unsigned u){ return __uint_as_float(u & 0xffff0000u); }

__device__ __forceinline__ void acc8(float* a, float w, uint4 r){
  a[0] += w*b2f_lo(r.x); a[1] += w*b2f_hi(r.x);
  a[2] += w*b2f_lo(r.y); a[3] += w*b2f_hi(r.y);
  a[4] += w*b2f_lo(r.z); a[5] += w*b2f_hi(r.z);
  a[6] += w*b2f_lo(r.w); a[7] += w*b2f_hi(r.w);
}

// ---------------- scan: thread-serial 2-pass ----------------
__global__ __launch_bounds__(1024) void scan_k(const int* __restrict__ deg, int N,
                                               int* __restrict__ off, int* __restrict__ cursor){
  __shared__ int wsum[16];
  int t = threadIdx.x, lane = t & 63, wid = t >> 6;
  int PER = (N + 1023) >> 10;
  int base = t * PER;
  int sum = 0;
  for (int i = 0; i < PER; ++i) {
    int idx = base + i;
    if (idx < N) sum += deg[idx];
  }
  int x = sum;
  #pragma unroll
  for (int o = 1; o < 64; o <<= 1) {
    int y = __shfl_up(x, o, 64);
    if (lane >= o) x += y;
  }
  if (lane == 63) wsum[wid] = x;
  __syncthreads();
  if (wid == 0 && lane < 16) {
    int wv = wsum[lane];
    #pragma unroll
    for (int o = 1; o < 16; o <<= 1) {
      int y = __shfl_up(wv, o, 16);
      if (lane >= o) wv += y;
    }
    wsum[lane] = wv;
  }
  __syncthreads();
  int carry = x - sum + (wid > 0 ? wsum[wid-1] : 0);
  int run = carry;
  for (int i = 0; i < PER; ++i) {
    int idx = base + i;
    if (idx < N) {
      off[idx] = run; cursor[idx] = run;
      run += deg[idx];
    }
  }
  if (base < N && base + PER >= N) off[N] = run;
}

__global__ void scatter_k(const int* __restrict__ ei, int E0, int N,
                          int* __restrict__ cursor, int* __restrict__ csr){
  int e = blockIdx.x*256 + threadIdx.x;
  int tot = E0 + N;
  if (e >= tot) return;
  int src, dst;
  if (e < E0) { src = ei[e]; dst = ei[E0 + e]; }
  else        { src = e - E0; dst = src; }
  int p = atomicAdd(&cursor[dst], 1);
  csr[p] = src;
}

// ---------------- prep: xcvt + w1t + w2t + ut(16 blocks) + hist ----------------
__global__ __launch_bounds__(256) void prep_k(const float* __restrict__ x,
    const float* __restrict__ W1, const float* __restrict__ W2,
    const float* __restrict__ a1s, const float* __restrict__ a1d,
    const int* __restrict__ ei,
    unsigned short* __restrict__ xb, unsigned short* __restrict__ w1t,
    unsigned short* __restrict__ w2t, unsigned short* __restrict__ ut_g,
    int* __restrict__ deg,
    int total8, int bX, int E0, int N){
  __shared__ unsigned short sT[FIN][64+2];
  int b = blockIdx.x, t = threadIdx.x;
  if (b < bX) {                       // x -> bf16
    int i = b*256 + t;
    if (i < total8) {
      const float4* p = (const float4*)x + (size_t)i*2;
      float4 a = p[0], c = p[1];
      uint4 o;
      o.x = (unsigned)f2b(a.x) | ((unsigned)f2b(a.y) << 16);
      o.y = (unsigned)f2b(a.z) | ((unsigned)f2b(a.w) << 16);
      o.z = (unsigned)f2b(c.x) | ((unsigned)f2b(c.y) << 16);
      o.w = (unsigned)f2b(c.z) | ((unsigned)f2b(c.w) << 16);
      ((uint4*)xb)[i] = o;
    }
    return;
  }
  b -= bX;
  if (b < 16) {                       // W1 -> bf16 transposed [n][k]
    int n0 = b * 64;
    #pragma unroll
    for (int i = 0; i < 32; ++i) {
      int idx = i*256 + t;
      int k = idx >> 6, nl = idx & 63;
      sT[k][nl] = f2b(W1[(size_t)k*HD + n0 + nl]);
    }
    __syncthreads();
    #pragma unroll
    for (int i = 0; i < 16; ++i) {
      int nl = i*4 + (t >> 6);
      int kp = t & 63;
      unsigned u = (unsigned)sT[2*kp][nl] | ((unsigned)sT[2*kp+1][nl] << 16);
      *(unsigned*)&w1t[(size_t)(n0+nl)*FIN + 2*kp] = u;
    }
    return;
  }
  b -= 16;
  if (b < (NW2*HD)/256) {             // W2 -> bf16 transposed padded [32][1024]
    int idx = b*256 + t;
    int n = idx >> 10, k = idx & 1023;
    w2t[idx] = (n < NC) ? f2b(W2[(size_t)k*NC + n]) : (unsigned short)0;
    return;
  }
  b -= (NW2*HD)/256;
  if (b < 16) {                       // ut: one block per column c; thread k<128 one dot
    int c = b;
    int h = c >> 1;
    const float* av = (c & 1) ? &a1d[h*HC] : &a1s[h*HC];
    if (t < FIN) {
      const float4* wr = (const float4*)&W1[(size_t)t*HD + h*HC];
      const float4* ap = (const float4*)av;
      float s = 0.f;
      #pragma unroll 8
      for (int q = 0; q < HC/4; ++q) {
        float4 w4 = wr[q], a4 = ap[q];
        s += w4.x*a4.x + w4.y*a4.y + w4.z*a4.z + w4.w*a4.w;
      }
      ut_g[c*FIN + t] = f2b(s);
    }
    return;
  }
  b -= 16;
  {                                   // hist
    int e = b*256 + t;
    int tot = E0 + N;
    if (e >= tot) return;
    int dst = (e < E0) ? ei[E0 + e] : (e - E0);
    atomicAdd(&deg[dst], 1);
  }
}

// ---------------- GEMM1 (MFMA bf16) + alpha-via-MFMA + coalesced C-write ----------------
__global__ __launch_bounds__(256) void gemm1_mfma_k(const unsigned short* __restrict__ xb,
    const unsigned short* __restrict__ w1t, const unsigned short* __restrict__ ut_g,
    unsigned short* __restrict__ g1b, float* __restrict__ as1, float* __restrict__ ad1,
    int N){
  __shared__ unsigned short sA[128][136];  // [m][k] staging, reused as bf16 C tile
  __shared__ unsigned short sB[128][136];  // [n][k]
  __shared__ unsigned short sU[16][136];   // folded alpha cols
  int t = threadIdx.x, lane = t & 63, wid = t >> 6;
  int bm = blockIdx.x * 128;
  int head = blockIdx.y;
  int bn = head * 128;
  #pragma unroll
  for (int i = 0; i < 2; ++i) {
    int idx = i*256 + t;
    int row = idx >> 2, seg = idx & 3;
    int gm = bm + row;
    uint4 a0,a1,a2,a3;
    if (gm < N) {
      const uint4* gp = (const uint4*)(xb + (size_t)gm*FIN + seg*32);
      a0 = gp[0]; a1 = gp[1]; a2 = gp[2]; a3 = gp[3];
    } else {
      a0 = a1 = a2 = a3 = make_uint4(0,0,0,0);
    }
    uint4* lp = (uint4*)&sA[row][seg*32];
    lp[0]=a0; lp[1]=a1; lp[2]=a2; lp[3]=a3;
  }
  #pragma unroll
  for (int i = 0; i < 2; ++i) {
    int idx = i*256 + t;
    int row = idx >> 2, seg = idx & 3;
    const uint4* gp = (const uint4*)(w1t + (size_t)(bn + row)*FIN + seg*32);
    uint4* lp = (uint4*)&sB[row][seg*32];
    lp[0]=gp[0]; lp[1]=gp[1]; lp[2]=gp[2]; lp[3]=gp[3];
  }
  bool alpha_blk = (head == 0);
  if (alpha_blk) {
    int row = t >> 4, seg = t & 15;
    *(uint4*)&sU[row][seg*8] = *(const uint4*)&ut_g[row*FIN + seg*8];
  }
  __syncthreads();
  int wr = wid >> 1, wc = wid & 1;
  int lr = lane & 15, kb = lane >> 4;
  bool alpha_wave = alpha_blk && (wc == 0);
  f32x4 acc[4][4];
  f32x4 accA[4];
  #pragma unroll
  for (int mi = 0; mi < 4; ++mi) {
    f32x4 z = {0.f,0.f,0.f,0.f};
    accA[mi] = z;
    #pragma unroll
    for (int ni = 0; ni < 4; ++ni) acc[mi][ni] = z;
  }
  #pragma unroll
  for (int ks = 0; ks < 4; ++ks) {
    int ko = ks*32 + kb*8;
    bf16x8 a[4], b[4];
    #pragma unroll
    for (int mi = 0; mi < 4; ++mi)
      a[mi] = *(const bf16x8*)&sA[wr*64 + mi*16 + lr][ko];
    #pragma unroll
    for (int ni = 0; ni < 4; ++ni)
      b[ni] = *(const bf16x8*)&sB[wc*64 + ni*16 + lr][ko];
    #pragma unroll
    for (int mi = 0; mi < 4; ++mi)
      #pragma unroll
      for (int ni = 0; ni < 4; ++ni)
        acc[mi][ni] = __builtin_amdgcn_mfma_f32_16x16x32_bf16(a[mi], b[ni], acc[mi][ni], 0, 0, 0);
    if (alpha_wave) {
      bf16x8 ub = *(const bf16x8*)&sU[lr][ko];
      #pragma unroll
      for (int mi = 0; mi < 4; ++mi)
        accA[mi] = __builtin_amdgcn_mfma_f32_16x16x32_bf16(a[mi], ub, accA[mi], 0, 0, 0);
    }
  }
  __syncthreads();   // MFMA LDS reads complete; sA reusable

  if (alpha_wave) {
    int hcol = lr >> 1;
    float* dst0 = (lr & 1) ? ad1 : as1;
    #pragma unroll
    for (int mi = 0; mi < 4; ++mi)
      #pragma unroll
      for (int r = 0; r < 4; ++r) {
        int row = bm + wr*64 + mi*16 + kb*4 + r;
        if (row < N) dst0[(size_t)row*NH + hcol] = accA[mi][r];
      }
  }
  #pragma unroll
  for (int mi = 0; mi < 4; ++mi)
    #pragma unroll
    for (int ni = 0; ni < 4; ++ni) {
      int col = wc*64 + ni*16 + lr;
      #pragma unroll
      for (int r = 0; r < 4; ++r)
        sA[wr*64 + mi*16 + kb*4 + r][col] = f2b(acc[mi][ni][r]);
    }
  __syncthreads();
  {
    int row = t >> 1, half = t & 1;
    int grow = bm + row;
    if (grow < N) {
      uint4* dst = (uint4*)(g1b + (size_t)grow*HD + bn + half*64);
      const uint4* src = (const uint4*)&sA[row][half*64];
      #pragma unroll
      for (int q = 0; q < 8; ++q) dst[q] = src[q];
    }
  }
}

// ---------------- attn1: wave-per-dst single-pass online softmax + chunk-4 gather ----------------
__global__ __launch_bounds__(256) void attn1_k(const unsigned short* __restrict__ g1b,
    const float* __restrict__ as1, const float* __restrict__ ad1,
    const int* __restrict__ off, const int* __restrict__ csr,
    const float* __restrict__ b1, unsigned short* __restrict__ hb, int N){
  int t = threadIdx.x, lane = t & 63, wid = t >> 6;
  int d = blockIdx.x*4 + wid;
  if (d >= N) return;
  int beg = off[d], deg = off[d+1] - beg;
  int hg = lane >> 3;
  float adg = ad1[d*NH + hg];
  float m = -1e30f, z = 0.f;
  float acc[16];
  #pragma unroll
  for (int i = 0; i < 16; ++i) acc[i] = 0.f;

  int j = 0;
  for (; j + 4 <= deg; j += 4) {
    int s0 = csr[beg+j+0], s1 = csr[beg+j+1], s2 = csr[beg+j+2], s3 = csr[beg+j+3];
    const uint4* p0 = (const uint4*)(g1b + (size_t)s0*HD) + lane*2;
    const uint4* p1 = (const uint4*)(g1b + (size_t)s1*HD) + lane*2;
    const uint4* p2 = (const uint4*)(g1b + (size_t)s2*HD) + lane*2;
    const uint4* p3 = (const uint4*)(g1b + (size_t)s3*HD) + lane*2;
    uint4 r00 = p0[0], r01 = p0[1];
    uint4 r10 = p1[0], r11 = p1[1];
    uint4 r20 = p2[0], r21 = p2[1];
    uint4 r30 = p3[0], r31 = p3[1];
    float e0 = lrelu(as1[s0*NH+hg] + adg);
    float e1 = lrelu(as1[s1*NH+hg] + adg);
    float e2 = lrelu(as1[s2*NH+hg] + adg);
    float e3 = lrelu(as1[s3*NH+hg] + adg);
    float em = fmaxf(fmaxf(e0,e1), fmaxf(e2,e3));
    if (em > m) {
      float sc = __expf(m - em);
      z *= sc;
      #pragma unroll
      for (int i = 0; i < 16; ++i) acc[i] *= sc;
      m = em;
    }
    float w0 = __expf(e0 - m), w1 = __expf(e1 - m);
    float w2 = __expf(e2 - m), w3 = __expf(e3 - m);
    z += w0 + w1 + w2 + w3;
    acc8(acc, w0, r00); acc8(acc+8, w0, r01);
    acc8(acc, w1, r10); acc8(acc+8, w1, r11);
    acc8(acc, w2, r20); acc8(acc+8, w2, r21);
    acc8(acc, w3, r30); acc8(acc+8, w3, r31);
  }
  for (; j < deg; ++j) {
    int s = csr[beg+j];
    const uint4* p = (const uint4*)(g1b + (size_t)s*HD) + lane*2;
    uint4 r0 = p[0], r1 = p[1];
    float e = lrelu(as1[s*NH+hg] + adg);
    if (e > m) {
      float sc = __expf(m - e);
      z *= sc;
      #pragma unroll
      for (int i = 0; i < 16; ++i) acc[i] *= sc;
      m = e;
    }
    float w = __expf(e - m);
    z += w;
    acc8(acc, w, r0); acc8(acc+8, w, r1);
  }

  float zinv = 1.f / (z + 1e-16f);
  int cb = lane*16;
  uint o[8];
  #pragma unroll
  for (int q = 0; q < 4; ++q) {
    float4 bv = *(const float4*)&b1[cb + q*4];
    float v0 = fmaxf(acc[q*4+0]*zinv + bv.x, 0.f);
    float v1 = fmaxf(acc[q*4+1]*zinv + bv.y, 0.f);
    float v2 = fmaxf(acc[q*4+2]*zinv + bv.z, 0.f);
    float v3 = fmaxf(acc[q*4+3]*zinv + bv.w, 0.f);
    o[q*2+0] = (unsigned)f2b(v0) | ((unsigned)f2b(v1) << 16);
    o[q*2+1] = (unsigned)f2b(v2) | ((unsigned)f2b(v3) << 16);
  }
  uint4* dst = (uint4*)(hb + (size_t)d*HD) + lane*2;
  dst[0] = make_uint4(o[0], o[1], o[2], o[3]);
  dst[1] = make_uint4(o[4], o[5], o[6], o[7]);
}

// ---------------- GEMM2 (MFMA) + fused alpha2 ----------------
__global__ __launch_bounds__(256) void gemm2_k(const unsigned short* __restrict__ hb,
    const unsigned short* __restrict__ w2t, const float* __restrict__ a2s_g, const float* __restrict__ a2d_g,
    float* __restrict__ g2, float* __restrict__ as2, float* __restrict__ ad2, int N){
  __shared__ float red[4][32][32];
  int t = threadIdx.x, lane = t & 63, wid = t >> 6;
  int bm = blockIdx.x * 32;
  int lr = lane & 15, kb = lane >> 4;
  int kw = wid * 256;
  f32x4 acc[2][2];
  #pragma unroll
  for (int mi = 0; mi < 2; ++mi)
    #pragma unroll
    for (int ni = 0; ni < 2; ++ni) {
      f32x4 z = {0.f,0.f,0.f,0.f};
      acc[mi][ni] = z;
    }
  bf16x8 zf;
  #pragma unroll
  for (int q = 0; q < 8; ++q) zf[q] = 0;
  int r0n = bm + lr, r1n = bm + 16 + lr;
  #pragma unroll
  for (int ks = 0; ks < 8; ++ks) {
    int k = kw + ks*32 + kb*8;
    bf16x8 a0 = (r0n < N) ? *(const bf16x8*)&hb[(size_t)r0n*HD + k] : zf;
    bf16x8 a1 = (r1n < N) ? *(const bf16x8*)&hb[(size_t)r1n*HD + k] : zf;
    bf16x8 b0 = *(const bf16x8*)&w2t[(size_t)lr*HD + k];
    bf16x8 b1 = *(const bf16x8*)&w2t[(size_t)(16+lr)*HD + k];
    acc[0][0] = __builtin_amdgcn_mfma_f32_16x16x32_bf16(a0, b0, acc[0][0], 0,0,0);
    acc[0][1] = __builtin_amdgcn_mfma_f32_16x16x32_bf16(a0, b1, acc[0][1], 0,0,0);
    acc[1][0] = __builtin_amdgcn_mfma_f32_16x16x32_bf16(a1, b0, acc[1][0], 0,0,0);
    acc[1][1] = __builtin_amdgcn_mfma_f32_16x16x32_bf16(a1, b1, acc[1][1], 0,0,0);
  }
  #pragma unroll
  for (int mi = 0; mi < 2; ++mi)
    #pragma unroll
    for (int ni = 0; ni < 2; ++ni)
      #pragma unroll
      for (int r = 0; r < 4; ++r)
        red[wid][mi*16 + kb*4 + r][ni*16 + lr] = acc[mi][ni][r];
  __syncthreads();
  int row = t >> 3;
  int c4 = (t & 7) * 4;
  float tot[4];
  #pragma unroll
  for (int q = 0; q < 4; ++q)
    tot[q] = red[0][row][c4+q] + red[1][row][c4+q] + red[2][row][c4+q] + red[3][row][c4+q];
  int n = bm + row;
  float ps = 0.f, pd = 0.f;
  #pragma unroll
  for (int q = 0; q < 4; ++q) {
    int c = c4 + q;
    if (c < NC) {
      ps += tot[q]*a2s_g[c];
      pd += tot[q]*a2d_g[c];
    }
  }
  #pragma unroll
  for (int o = 1; o < 8; o <<= 1) {
    ps += __shfl_xor(ps, o, 8);
    pd += __shfl_xor(pd, o, 8);
  }
  if (n < N) {
    #pragma unroll
    for (int q = 0; q < 4; ++q) {
      int c = c4 + q;
      if (c < NC) g2[(size_t)n*NC + c] = tot[q];
    }
    if ((t & 7) == 0) { as2[n] = ps; ad2[n] = pd; }
  }
}

// ---------------- attn2: wave-per-dst single-pass, 3x18-lane edge-parallel ----------------
__global__ __launch_bounds__(256) void attn2_k(const float* __restrict__ g2,
    const float* __restrict__ as2, const float* __restrict__ ad2,
    const int* __restrict__ off, const int* __restrict__ csr,
    const float* __restrict__ b2, float* __restrict__ out, int N){
  int t = threadIdx.x, lane = t & 63, wid = t >> 6;
  int d = blockIdx.x*4 + wid;
  if (d >= N) return;
  int beg = off[d], deg = off[d+1] - beg;
  float adv = ad2[d];
  int g = lane / 18;
  int c = lane - g*18;
  float m = -1e30f, z = 0.f, acc = 0.f;
  if (g < 3) {
    int j = g;
    for (; j + 3 < deg; j += 6) {
      int sa = csr[beg+j], sb = csr[beg+j+3];
      float va = g2[(size_t)sa*NC + c];
      float vb = g2[(size_t)sb*NC + c];
      float ea = lrelu(as2[sa] + adv);
      float eb = lrelu(as2[sb] + adv);
      float em = fmaxf(ea, eb);
      if (em > m) { float sc = __expf(m - em); z *= sc; acc *= sc; m = em; }
      float wa = __expf(ea - m), wb = __expf(eb - m);
      z += wa + wb;
      acc += wa*va + wb*vb;
    }
    for (; j < deg; j += 3) {
      int s = csr[beg+j];
      float v = g2[(size_t)s*NC + c];
      float e = lrelu(as2[s] + adv);
      if (e > m) { float sc = __expf(m - e); z *= sc; acc *= sc; m = e; }
      float w = __expf(e - m);
      z += w;
      acc += w*v;
    }
  }
  float m0 = __shfl(m, 0),  m1 = __shfl(m, 18), m2 = __shfl(m, 36);
  float M  = fmaxf(m0, fmaxf(m1, m2));
  float e0 = __expf(m0 - M), e1 = __expf(m1 - M), e2 = __expf(m2 - M);
  float z0 = __shfl(z, 0),  z1 = __shfl(z, 18), z2 = __shfl(z, 36);
  int cl = (lane < NC) ? lane : 0;
  float a0 = __shfl(acc, cl), a1 = __shfl(acc, cl+18), a2 = __shfl(acc, cl+36);
  if (lane < NC) {
    float Z = z0*e0 + z1*e1 + z2*e2;
    float A = a0*e0 + a1*e1 + a2*e2;
    out[(size_t)d*NC + lane] = A / (Z + 1e-16f) + b2[lane];
  }
}

extern "C" void kernel_launch(void* const* d_in, const int* in_sizes, int n_in,
                              void* d_out, int out_size, void* d_ws, size_t ws_size,
                              hipStream_t stream){
  const float* x   = (const float*)d_in[0];
  const int*   ei  = (const int*)d_in[1];
  const float* W1  = (const float*)d_in[2];
  const float* a1s = (const float*)d_in[3];
  const float* a1d = (const float*)d_in[4];
  const float* b1  = (const float*)d_in[5];
  const float* W2  = (const float*)d_in[6];
  const float* a2s = (const float*)d_in[7];
  const float* a2d = (const float*)d_in[8];
  const float* b2  = (const float*)d_in[9];
  float* out = (float*)d_out;
  int N  = in_sizes[0] / FIN;
  int E0 = in_sizes[1] / 2;
  int Etot = E0 + N;

  // fp32 region
  float* as1 = (float*)d_ws;                 // N*8
  float* ad1 = as1 + (size_t)N*NH;           // N*8
  float* g2  = ad1 + (size_t)N*NH;           // N*18
  float* as2 = g2 + (size_t)N*NC;            // N
  float* ad2 = as2 + N;                      // N
  // bf16 region
  unsigned short* g1b = (unsigned short*)(ad2 + N);       // N*1024
  unsigned short* hb  = g1b + (size_t)N*HD;               // N*1024
  // int region
  int* deg    = (int*)(hb + (size_t)N*HD);
  int* off    = deg + N;
  int* cursor = off + N + 4;
  int* csr    = cursor + N;
  // bf16 w2t [32][1024] + ut [16][128]
  unsigned short* w2t  = (unsigned short*)(csr + Etot);   // 32*1024
  unsigned short* ut_g = w2t + (size_t)NW2*HD;            // 16*128
  // converted inputs alias hb
  unsigned short* xb  = hb;                   // N*FIN
  unsigned short* w1t = hb + (size_t)N*FIN;   // HD*FIN

  hipMemsetAsync(deg, 0, sizeof(int)*(size_t)N, stream);

  int total8 = N*FIN/8;
  int bX = (total8 + 255)/256;
  int bH = (Etot + 255)/256;
  int bW2 = (NW2*HD)/256;   // 128
  prep_k<<<bX + 16 + bW2 + 16 + bH, 256, 0, stream>>>(x, W1, W2, a1s, a1d, ei,
                                                      xb, w1t, w2t, ut_g, deg,
                                                      total8, bX, E0, N);
  scan_k<<<1, 1024, 0, stream>>>(deg, N, off, cursor);
  scatter_k<<<(Etot+255)/256, 256, 0, stream>>>(ei, E0, N, cursor, csr);

  dim3 g1grid((N+127)/128, HD/128);
  gemm1_mfma_k<<<g1grid, 256, 0, stream>>>(xb, w1t, ut_g, g1b, as1, ad1, N);
  attn1_k<<<(N+3)/4, 256, 0, stream>>>(g1b, as1, ad1, off, csr, b1, hb, N);
  gemm2_k<<<(N+31)/32, 256, 0, stream>>>(hb, w2t, a2s, a2d, g2, as2, ad2, N);
  attn2_k<<<(N+3)/4, 256, 0, stream>>>(g2, as2, ad2, off, csr, b2, out, N);
}